// Round 7
// baseline (120.166 us; speedup 1.0000x reference)
//
#include <hip/hip_runtime.h>
#include <math.h>

#define IN_DIM 256
#define HD 256
#define EDGE_DIM 32
#define NEG_SLOPE 0.2f
#define CAP 128
#define PSTRIDE 136

typedef _Float16 f16x8 __attribute__((ext_vector_type(8)));
typedef _Float16 f16x4 __attribute__((ext_vector_type(4)));
typedef float f32x4 __attribute__((ext_vector_type(4)));

__device__ __forceinline__ void load_edge(const int* ei, int e, int E, int n, int is64,
                                          int& s, int& d) {
    if (e < E) {
        if (is64) { s = ei[2 * e]; d = ei[2 * E + 2 * e]; }
        else      { s = ei[e];     d = ei[E + e]; }
    } else {
        s = d = e - E;  // self loop
    }
}

__device__ __forceinline__ f16x8 cvt8(const float* p) {
    float4 lo = *(const float4*)p;
    float4 hi = *(const float4*)(p + 4);
    auto a = __builtin_amdgcn_cvt_pkrtz(lo.x, lo.y);
    auto b = __builtin_amdgcn_cvt_pkrtz(lo.z, lo.w);
    auto c = __builtin_amdgcn_cvt_pkrtz(hi.x, hi.y);
    auto d = __builtin_amdgcn_cvt_pkrtz(hi.z, hi.w);
    f16x8 r;
    r[0] = (_Float16)a[0]; r[1] = (_Float16)a[1];
    r[2] = (_Float16)b[0]; r[3] = (_Float16)b[1];
    r[4] = (_Float16)c[0]; r[5] = (_Float16)c[1];
    r[6] = (_Float16)d[0]; r[7] = (_Float16)d[1];
    return r;
}

// ---------- zero deg (replaces hipMemsetAsync: runtime fill kernel cost ~40us!) ----------
__global__ __launch_bounds__(256) void zero_kernel(int* __restrict__ deg, int n4) {
    int i = (blockIdx.x * 256 + threadIdx.x) * 4;
    if (i < n4) *(int4*)&deg[i] = make_int4(0, 0, 0, 0);
}

// ---------- prep: weff (b0), detect (b1), W->fp16 (b2..33), deg histogram + perm (b34..) ----
// deg[] must be zeroed before this kernel. Histogram blocks do their own int64-detect.
// perm[e] = within-bucket ordinal of edge e (histogram atomic's return value).
#define WCVT_BLOCKS 32
__global__ __launch_bounds__(256) void prep_kernel(const int* __restrict__ ei,
                                                   const float* __restrict__ lew,
                                                   const float* __restrict__ ae,
                                                   const float* __restrict__ W,
                                                   float* __restrict__ weff,
                                                   _Float16* __restrict__ Wh,
                                                   int* __restrict__ deg,
                                                   int* __restrict__ perm,
                                                   int* __restrict__ flag, int E, int n) {
    int b = blockIdx.x;
    int t = threadIdx.x;
    if (b == 0) {
        if (t < 128) {
            int h = t >> 5, k = t & 31;
            float s = 0.f;
#pragma unroll 8
            for (int d = 0; d < 64; ++d) s += lew[(h * 64 + d) * 32 + k] * ae[h * 64 + d];
            weff[t] = s;
        }
    } else if (b == 1) {
        __shared__ int anynz;
        if (t == 0) anynz = 0;
        __syncthreads();
        if (ei[2 * t + 1] != 0) atomicOr(&anynz, 1);
        __syncthreads();
        if (t == 0) *flag = (anynz == 0) ? 1 : 0;
    } else if (b < 2 + WCVT_BLOCKS) {
        int idx = (b - 2) * 2048 + t * 8;
        *(f16x8*)&Wh[idx] = cvt8(&W[idx]);
    } else {
        // degree histogram + perm, 4 edges per thread, block-local detect
        __shared__ int anynz;
        if (t == 0) anynz = 0;
        __syncthreads();
        if (ei[2 * t + 1] != 0) atomicOr(&anynz, 1);
        __syncthreads();
        int is64 = (anynz == 0);
        int e0 = ((b - 2 - WCVT_BLOCKS) * 256 + t) * 4;
        if (e0 >= E) return;
        if (e0 + 4 <= E) {
            int4 pm;
            if (!is64) {
                int4 d4 = *(const int4*)&ei[E + e0];
                pm.x = atomicAdd(&deg[d4.x], 1);
                pm.y = atomicAdd(&deg[d4.y], 1);
                pm.z = atomicAdd(&deg[d4.z], 1);
                pm.w = atomicAdd(&deg[d4.w], 1);
            } else {
                int4 a = *(const int4*)&ei[2 * E + 2 * e0];
                int4 b4 = *(const int4*)&ei[2 * E + 2 * e0 + 4];
                pm.x = atomicAdd(&deg[a.x], 1);
                pm.y = atomicAdd(&deg[a.z], 1);
                pm.z = atomicAdd(&deg[b4.x], 1);
                pm.w = atomicAdd(&deg[b4.z], 1);
            }
            *(int4*)&perm[e0] = pm;
        } else {
            for (int e = e0; e < E && e < e0 + 4; ++e) {
                int d = is64 ? ei[2 * E + 2 * e] : ei[E + e];
                perm[e] = atomicAdd(&deg[d], 1);
            }
        }
    }
}

// ---------- x_proj (fp16) via MFMA, 16 rows/block, fused s_src/s_dst epilogue ----------
__global__ __launch_bounds__(256) void proj_kernel(const float* __restrict__ x,
                                                   const _Float16* __restrict__ Wh,
                                                   const float* __restrict__ asrc_g,
                                                   const float* __restrict__ adst_g,
                                                   _Float16* __restrict__ xph,
                                                   float* __restrict__ s_src,
                                                   float* __restrict__ s_dst, int n) {
    int tid = threadIdx.x;
    int lane = tid & 63;
    int w = tid >> 6;            // wave id == head id (col group)
    int m0 = blockIdx.x * 16;
    int c0 = w * 64;
    int r = lane & 15;
    int kq = lane >> 4;          // 0..3

    float asr[4], ads[4];
#pragma unroll
    for (int ci = 0; ci < 4; ++ci) {
        asr[ci] = asrc_g[c0 + ci * 16 + r];
        ads[ci] = adst_g[c0 + ci * 16 + r];
    }

    f32x4 acc[4];
#pragma unroll
    for (int j = 0; j < 4; ++j) acc[j] = (f32x4){0.f, 0.f, 0.f, 0.f};

    int row = m0 + r;
    bool rok = row < n;
#pragma unroll
    for (int k0 = 0; k0 < IN_DIM; k0 += 32) {
        int kk = k0 + kq * 8;
        f16x8 a = {0, 0, 0, 0, 0, 0, 0, 0};
        if (rok) a = cvt8(&x[(size_t)row * IN_DIM + kk]);
        f16x8 bfr[4];
#pragma unroll
        for (int ci = 0; ci < 4; ++ci)
            bfr[ci] = *(const f16x8*)&Wh[(size_t)(c0 + ci * 16 + r) * IN_DIM + kk];
#pragma unroll
        for (int ci = 0; ci < 4; ++ci)
            acc[ci] = __builtin_amdgcn_mfma_f32_16x16x32_f16(a, bfr[ci], acc[ci], 0, 0, 0);
    }
    // C/D layout: col = lane&15, row = (lane>>4)*4 + j
#pragma unroll
    for (int j = 0; j < 4; ++j) {
        int orow = m0 + kq * 4 + j;
        if (orow < n) {
#pragma unroll
            for (int ci = 0; ci < 4; ++ci)
                xph[(size_t)orow * HD + c0 + ci * 16 + r] = (_Float16)acc[ci][j];
        }
    }
    // fused attention scores: wave w == head w owns cols [w*64, w*64+64)
#pragma unroll
    for (int j = 0; j < 4; ++j) {
        float vs = 0.f, vd = 0.f;
#pragma unroll
        for (int ci = 0; ci < 4; ++ci) {
            vs += acc[ci][j] * asr[ci];
            vd += acc[ci][j] * ads[ci];
        }
#pragma unroll
        for (int msk = 1; msk < 16; msk <<= 1) {
            vs += __shfl_xor(vs, msk);
            vd += __shfl_xor(vd, msk);
        }
        int orow = m0 + kq * 4 + j;
        if (r == 0 && orow < n) {
            s_src[orow * 4 + w] = vs;
            s_dst[orow * 4 + w] = vd;
        }
    }
}

// ---------- single-block exclusive scan over (deg+1), int4-vectorized ----------
#define SCAN_T 1024
__global__ __launch_bounds__(SCAN_T) void scan_kernel(const int* __restrict__ deg,
                                                      int* __restrict__ rowptr, int n) {
    __shared__ int sdata[SCAN_T];
    int t = threadIdx.x;
    int per = (n + SCAN_T - 1) / SCAN_T;
    int begin = t * per;
    int endi = begin + per;
    if (endi > n) endi = n;
    if (begin > n) begin = n;
    bool vec = ((begin & 3) == 0) && (((endi - begin) & 3) == 0);
    int s = 0;
    if (vec) {
        for (int i = begin; i < endi; i += 4) {
            int4 v = *(const int4*)&deg[i];
            s += v.x + v.y + v.z + v.w + 4;
        }
    } else {
        for (int i = begin; i < endi; ++i) s += deg[i] + 1;
    }
    sdata[t] = s;
    __syncthreads();
    for (int off = 1; off < SCAN_T; off <<= 1) {
        int v = 0;
        if (t >= off) v = sdata[t - off];
        __syncthreads();
        sdata[t] += v;
        __syncthreads();
    }
    int run = (t == 0) ? 0 : sdata[t - 1];
    if (vec) {
        for (int i = begin; i < endi; i += 4) {
            int4 v = *(const int4*)&deg[i];
            int4 o;
            o.x = run; run += v.x + 1;
            o.y = run; run += v.y + 1;
            o.z = run; run += v.z + 1;
            o.w = run; run += v.w + 1;
            *(int4*)&rowptr[i] = o;
        }
    } else {
        for (int i = begin; i < endi; ++i) {
            rowptr[i] = run;
            run += deg[i] + 1;
        }
    }
    if (t == SCAN_T - 1) rowptr[n] = run;
}

// ---------- edge scoring + exp + CSR placement (atomic-free) ----------
__global__ __launch_bounds__(256) void edge_kernel(const int* __restrict__ ei,
                                                   const float* __restrict__ ea,
                                                   const float* __restrict__ s_src,
                                                   const float* __restrict__ s_dst,
                                                   const float* __restrict__ weff,
                                                   const int* __restrict__ flag,
                                                   const int* __restrict__ rowptr,
                                                   const int* __restrict__ perm,
                                                   int* __restrict__ src_csr,
                                                   float* __restrict__ p_csr,
                                                   int E, int n) {
    __shared__ float we[128];
    if (threadIdx.x < 128) we[threadIdx.x] = weff[threadIdx.x];
    __syncthreads();
    int e = blockIdx.x * blockDim.x + threadIdx.x;
    int EP = E + n;
    if (e >= EP) return;
    int is64 = *flag;
    int s, d;
    load_edge(ei, e, E, n, is64, s, d);
    int pos;
    if (e < E) pos = rowptr[d] + perm[e];
    else       pos = rowptr[d + 1] - 1;   // self-loop takes last slot of bucket
    float4 vs = *(const float4*)&s_src[(size_t)s * 4];
    float4 vd = *(const float4*)&s_dst[(size_t)d * 4];
    float ed[4] = {0.f, 0.f, 0.f, 0.f};
    if (e < E) {
#pragma unroll
        for (int k = 0; k < EDGE_DIM; k += 4) {
            float4 v = *(const float4*)&ea[(size_t)e * EDGE_DIM + k];
#pragma unroll
            for (int h = 0; h < 4; ++h) {
                ed[h] += v.x * we[h * 32 + k + 0] + v.y * we[h * 32 + k + 1] +
                         v.z * we[h * 32 + k + 2] + v.w * we[h * 32 + k + 3];
            }
        }
    }
    float t0 = vs.x + vd.x + ed[0];
    float t1 = vs.y + vd.y + ed[1];
    float t2 = vs.z + vd.z + ed[2];
    float t3 = vs.w + vd.w + ed[3];
    t0 = t0 >= 0.f ? t0 : NEG_SLOPE * t0;
    t1 = t1 >= 0.f ? t1 : NEG_SLOPE * t1;
    t2 = t2 >= 0.f ? t2 : NEG_SLOPE * t2;
    t3 = t3 >= 0.f ? t3 : NEG_SLOPE * t3;
    float4 o;
    o.x = __expf(t0);
    o.y = __expf(t1);
    o.z = __expf(t2);
    o.w = __expf(t3);
    src_csr[pos] = s;
    *(float4*)&p_csr[(size_t)pos * 4] = o;
}

// ---------- softmax + aggregation: one wave per node, 2 passes, LDS-cached p ----------
__global__ __launch_bounds__(256) void agg_kernel(const int* __restrict__ rowptr,
                                                  const int* __restrict__ src_csr,
                                                  const float* __restrict__ p_csr,
                                                  const _Float16* __restrict__ xph,
                                                  const float* __restrict__ bias,
                                                  float* __restrict__ out, int n) {
    __shared__ float pl[4][4 * PSTRIDE];
    int wv = threadIdx.x >> 6;
    float* pbuf = pl[wv];
    int wid = (blockIdx.x * blockDim.x + threadIdx.x) >> 6;
    int lane = threadIdx.x & 63;
    if (wid >= n) return;
    int start = rowptr[wid];
    int end = rowptr[wid + 1];
    int deg = end - start;

    float d0 = 0.f, d1 = 0.f, d2 = 0.f, d3 = 0.f;
    for (int i = start + lane; i < end; i += 64) {
        float4 a = *(const float4*)&p_csr[(size_t)i * 4];
        int idx = i - start;
        if (idx < CAP) {
            pbuf[0 * PSTRIDE + idx] = a.x;
            pbuf[1 * PSTRIDE + idx] = a.y;
            pbuf[2 * PSTRIDE + idx] = a.z;
            pbuf[3 * PSTRIDE + idx] = a.w;
        }
        d0 += a.x; d1 += a.y; d2 += a.z; d3 += a.w;
    }
#pragma unroll
    for (int o = 1; o < 64; o <<= 1) {
        d0 += __shfl_xor(d0, o);
        d1 += __shfl_xor(d1, o);
        d2 += __shfl_xor(d2, o);
        d3 += __shfl_xor(d3, o);
    }
    int h = lane >> 4;
    float dh = h == 0 ? d0 : (h == 1 ? d1 : (h == 2 ? d2 : d3));
    float invh = 1.f / (dh + 1e-12f);
    const float* ph = &pbuf[h * PSTRIDE];

    float ax = 0.f, ay = 0.f, az = 0.f, aw = 0.f;
    int idx = 0;
    for (; idx + 2 <= deg; idx += 2) {
        int s0 = src_csr[start + idx];
        int s1 = src_csr[start + idx + 1];
        float p0 = (idx < CAP) ? ph[idx] : p_csr[(size_t)(start + idx) * 4 + h];
        float p1 = (idx + 1 < CAP) ? ph[idx + 1] : p_csr[(size_t)(start + idx + 1) * 4 + h];
        f16x4 x0 = *(const f16x4*)&xph[(size_t)s0 * HD + lane * 4];
        f16x4 x1 = *(const f16x4*)&xph[(size_t)s1 * HD + lane * 4];
        float al0 = p0 * invh;
        float al1 = p1 * invh;
        ax += al0 * (float)x0[0] + al1 * (float)x1[0];
        ay += al0 * (float)x0[1] + al1 * (float)x1[1];
        az += al0 * (float)x0[2] + al1 * (float)x1[2];
        aw += al0 * (float)x0[3] + al1 * (float)x1[3];
    }
    if (idx < deg) {
        int s0 = src_csr[start + idx];
        float p0 = (idx < CAP) ? ph[idx] : p_csr[(size_t)(start + idx) * 4 + h];
        f16x4 x0 = *(const f16x4*)&xph[(size_t)s0 * HD + lane * 4];
        float al0 = p0 * invh;
        ax += al0 * (float)x0[0];
        ay += al0 * (float)x0[1];
        az += al0 * (float)x0[2];
        aw += al0 * (float)x0[3];
    }
    float4 b = *(const float4*)&bias[lane * 4];
    float4 o4;
    o4.x = ax + b.x; o4.y = ay + b.y; o4.z = az + b.z; o4.w = aw + b.w;
    *(float4*)&out[(size_t)wid * HD + lane * 4] = o4;
}

extern "C" void kernel_launch(void* const* d_in, const int* in_sizes, int n_in,
                              void* d_out, int out_size, void* d_ws, size_t ws_size,
                              hipStream_t stream) {
    const float* x        = (const float*)d_in[0];
    const int*   ei       = (const int*)d_in[1];
    const float* ea       = (const float*)d_in[2];
    const float* lin_W    = (const float*)d_in[3];
    const float* att_src  = (const float*)d_in[4];
    const float* att_dst  = (const float*)d_in[5];
    const float* lin_eW   = (const float*)d_in[6];
    const float* att_edge = (const float*)d_in[7];
    const float* bias     = (const float*)d_in[8];
    float* out = (float*)d_out;

    int n  = in_sizes[0] / IN_DIM;     // 20000
    int E  = in_sizes[2] / EDGE_DIM;   // 320000
    int EP = E + n;

    char* p = (char*)d_ws;
    auto alloc = [&](size_t bytes) {
        char* r = p;
        p += (bytes + 255) & ~(size_t)255;
        return r;
    };
    _Float16* xph   = (_Float16*)alloc((size_t)n * HD * 2);
    _Float16* Wh    = (_Float16*)alloc((size_t)HD * IN_DIM * 2);
    float* s_src    = (float*)alloc((size_t)n * 4 * 4);
    float* s_dst    = (float*)alloc((size_t)n * 4 * 4);
    float* p_csr    = (float*)alloc((size_t)EP * 4 * 4);
    float* weff     = (float*)alloc(128 * 4);
    int*   deg      = (int*)alloc((size_t)(n + 4) * 4);
    int*   rowptr   = (int*)alloc((size_t)(n + 1) * 4);
    int*   perm     = (int*)alloc((size_t)E * 4);
    int*   src_csr  = (int*)alloc((size_t)EP * 4);
    int*   flag     = (int*)alloc(4);

    int n4 = (n + 3) & ~3;
    zero_kernel<<<(n4 / 4 + 255) / 256, 256, 0, stream>>>(deg, n4);
    int hist_blocks = (E + 1023) / 1024;
    prep_kernel<<<2 + WCVT_BLOCKS + hist_blocks, 256, 0, stream>>>(
        ei, lin_eW, att_edge, lin_W, weff, Wh, deg, perm, flag, E, n);
    proj_kernel<<<(n + 15) / 16, 256, 0, stream>>>(x, Wh, att_src, att_dst, xph,
                                                   s_src, s_dst, n);
    scan_kernel<<<1, SCAN_T, 0, stream>>>(deg, rowptr, n);
    edge_kernel<<<(EP + 255) / 256, 256, 0, stream>>>(ei, ea, s_src, s_dst, weff, flag,
                                                      rowptr, perm, src_csr, p_csr, E, n);
    agg_kernel<<<(n + 3) / 4, 256, 0, stream>>>(rowptr, src_csr, p_csr, xph, bias, out, n);
}

// Round 8
// 113.630 us; speedup vs baseline: 1.0575x; 1.0575x over previous
//
#include <hip/hip_runtime.h>
#include <math.h>

#define IN_DIM 256
#define HD 256
#define EDGE_DIM 32
#define NEG_SLOPE 0.2f

typedef _Float16 f16x8 __attribute__((ext_vector_type(8)));
typedef _Float16 f16x4 __attribute__((ext_vector_type(4)));
typedef float f32x4 __attribute__((ext_vector_type(4)));

__device__ __forceinline__ void load_edge(const int* ei, int e, int E, int n, int is64,
                                          int& s, int& d) {
    if (e < E) {
        if (is64) { s = ei[2 * e]; d = ei[2 * E + 2 * e]; }
        else      { s = ei[e];     d = ei[E + e]; }
    } else {
        s = d = e - E;  // self loop
    }
}

__device__ __forceinline__ f16x8 cvt8(const float* p) {
    float4 lo = *(const float4*)p;
    float4 hi = *(const float4*)(p + 4);
    auto a = __builtin_amdgcn_cvt_pkrtz(lo.x, lo.y);
    auto b = __builtin_amdgcn_cvt_pkrtz(lo.z, lo.w);
    auto c = __builtin_amdgcn_cvt_pkrtz(hi.x, hi.y);
    auto d = __builtin_amdgcn_cvt_pkrtz(hi.z, hi.w);
    f16x8 r;
    r[0] = (_Float16)a[0]; r[1] = (_Float16)a[1];
    r[2] = (_Float16)b[0]; r[3] = (_Float16)b[1];
    r[4] = (_Float16)c[0]; r[5] = (_Float16)c[1];
    r[6] = (_Float16)d[0]; r[7] = (_Float16)d[1];
    return r;
}

// ---------- zero deg ----------
__global__ __launch_bounds__(256) void zero_kernel(int* __restrict__ deg, int n4) {
    int i = (blockIdx.x * 256 + threadIdx.x) * 4;
    if (i < n4) *(int4*)&deg[i] = make_int4(0, 0, 0, 0);
}

// ---------- prep: weff (b0), detect (b1), W->fp16 (b2..33), deg histogram + perm (b34..) ----
// deg[] must be zeroed before this kernel. Histogram blocks do their own int64-detect.
// perm[e] = within-bucket ordinal of edge e (histogram atomic's return value).
#define WCVT_BLOCKS 32
__global__ __launch_bounds__(256) void prep_kernel(const int* __restrict__ ei,
                                                   const float* __restrict__ lew,
                                                   const float* __restrict__ ae,
                                                   const float* __restrict__ W,
                                                   float* __restrict__ weff,
                                                   _Float16* __restrict__ Wh,
                                                   int* __restrict__ deg,
                                                   int* __restrict__ perm,
                                                   int* __restrict__ flag, int E, int n) {
    int b = blockIdx.x;
    int t = threadIdx.x;
    if (b == 0) {
        if (t < 128) {
            int h = t >> 5, k = t & 31;
            float s = 0.f;
#pragma unroll 8
            for (int d = 0; d < 64; ++d) s += lew[(h * 64 + d) * 32 + k] * ae[h * 64 + d];
            weff[t] = s;
        }
    } else if (b == 1) {
        __shared__ int anynz;
        if (t == 0) anynz = 0;
        __syncthreads();
        if (ei[2 * t + 1] != 0) atomicOr(&anynz, 1);
        __syncthreads();
        if (t == 0) *flag = (anynz == 0) ? 1 : 0;
    } else if (b < 2 + WCVT_BLOCKS) {
        int idx = (b - 2) * 2048 + t * 8;
        *(f16x8*)&Wh[idx] = cvt8(&W[idx]);
    } else {
        // degree histogram + perm, 4 edges per thread, block-local detect
        __shared__ int anynz;
        if (t == 0) anynz = 0;
        __syncthreads();
        if (ei[2 * t + 1] != 0) atomicOr(&anynz, 1);
        __syncthreads();
        int is64 = (anynz == 0);
        int e0 = ((b - 2 - WCVT_BLOCKS) * 256 + t) * 4;
        if (e0 >= E) return;
        if (e0 + 4 <= E) {
            int4 pm;
            if (!is64) {
                int4 d4 = *(const int4*)&ei[E + e0];
                pm.x = atomicAdd(&deg[d4.x], 1);
                pm.y = atomicAdd(&deg[d4.y], 1);
                pm.z = atomicAdd(&deg[d4.z], 1);
                pm.w = atomicAdd(&deg[d4.w], 1);
            } else {
                int4 a = *(const int4*)&ei[2 * E + 2 * e0];
                int4 b4 = *(const int4*)&ei[2 * E + 2 * e0 + 4];
                pm.x = atomicAdd(&deg[a.x], 1);
                pm.y = atomicAdd(&deg[a.z], 1);
                pm.z = atomicAdd(&deg[b4.x], 1);
                pm.w = atomicAdd(&deg[b4.z], 1);
            }
            *(int4*)&perm[e0] = pm;
        } else {
            for (int e = e0; e < E && e < e0 + 4; ++e) {
                int d = is64 ? ei[2 * E + 2 * e] : ei[E + e];
                perm[e] = atomicAdd(&deg[d], 1);
            }
        }
    }
}

// ---------- x_proj (fp16) via MFMA, 16 rows/block, fused s_src/s_dst epilogue ----------
__global__ __launch_bounds__(256) void proj_kernel(const float* __restrict__ x,
                                                   const _Float16* __restrict__ Wh,
                                                   const float* __restrict__ asrc_g,
                                                   const float* __restrict__ adst_g,
                                                   _Float16* __restrict__ xph,
                                                   float* __restrict__ s_src,
                                                   float* __restrict__ s_dst, int n) {
    int tid = threadIdx.x;
    int lane = tid & 63;
    int w = tid >> 6;            // wave id == head id (col group)
    int m0 = blockIdx.x * 16;
    int c0 = w * 64;
    int r = lane & 15;
    int kq = lane >> 4;          // 0..3

    float asr[4], ads[4];
#pragma unroll
    for (int ci = 0; ci < 4; ++ci) {
        asr[ci] = asrc_g[c0 + ci * 16 + r];
        ads[ci] = adst_g[c0 + ci * 16 + r];
    }

    f32x4 acc[4];
#pragma unroll
    for (int j = 0; j < 4; ++j) acc[j] = (f32x4){0.f, 0.f, 0.f, 0.f};

    int row = m0 + r;
    bool rok = row < n;
#pragma unroll
    for (int k0 = 0; k0 < IN_DIM; k0 += 32) {
        int kk = k0 + kq * 8;
        f16x8 a = {0, 0, 0, 0, 0, 0, 0, 0};
        if (rok) a = cvt8(&x[(size_t)row * IN_DIM + kk]);
        f16x8 bfr[4];
#pragma unroll
        for (int ci = 0; ci < 4; ++ci)
            bfr[ci] = *(const f16x8*)&Wh[(size_t)(c0 + ci * 16 + r) * IN_DIM + kk];
#pragma unroll
        for (int ci = 0; ci < 4; ++ci)
            acc[ci] = __builtin_amdgcn_mfma_f32_16x16x32_f16(a, bfr[ci], acc[ci], 0, 0, 0);
    }
    // C/D layout: col = lane&15, row = (lane>>4)*4 + j
#pragma unroll
    for (int j = 0; j < 4; ++j) {
        int orow = m0 + kq * 4 + j;
        if (orow < n) {
#pragma unroll
            for (int ci = 0; ci < 4; ++ci)
                xph[(size_t)orow * HD + c0 + ci * 16 + r] = (_Float16)acc[ci][j];
        }
    }
    // fused attention scores: wave w == head w owns cols [w*64, w*64+64)
#pragma unroll
    for (int j = 0; j < 4; ++j) {
        float vs = 0.f, vd = 0.f;
#pragma unroll
        for (int ci = 0; ci < 4; ++ci) {
            vs += acc[ci][j] * asr[ci];
            vd += acc[ci][j] * ads[ci];
        }
#pragma unroll
        for (int msk = 1; msk < 16; msk <<= 1) {
            vs += __shfl_xor(vs, msk);
            vd += __shfl_xor(vd, msk);
        }
        int orow = m0 + kq * 4 + j;
        if (r == 0 && orow < n) {
            s_src[orow * 4 + w] = vs;
            s_dst[orow * 4 + w] = vd;
        }
    }
}

// ---------- single-block exclusive scan over (deg+1), int4-vectorized ----------
#define SCAN_T 1024
__global__ __launch_bounds__(SCAN_T) void scan_kernel(const int* __restrict__ deg,
                                                      int* __restrict__ rowptr, int n) {
    __shared__ int sdata[SCAN_T];
    int t = threadIdx.x;
    int per = (n + SCAN_T - 1) / SCAN_T;
    int begin = t * per;
    int endi = begin + per;
    if (endi > n) endi = n;
    if (begin > n) begin = n;
    bool vec = ((begin & 3) == 0) && (((endi - begin) & 3) == 0);
    int s = 0;
    if (vec) {
        for (int i = begin; i < endi; i += 4) {
            int4 v = *(const int4*)&deg[i];
            s += v.x + v.y + v.z + v.w + 4;
        }
    } else {
        for (int i = begin; i < endi; ++i) s += deg[i] + 1;
    }
    sdata[t] = s;
    __syncthreads();
    for (int off = 1; off < SCAN_T; off <<= 1) {
        int v = 0;
        if (t >= off) v = sdata[t - off];
        __syncthreads();
        sdata[t] += v;
        __syncthreads();
    }
    int run = (t == 0) ? 0 : sdata[t - 1];
    if (vec) {
        for (int i = begin; i < endi; i += 4) {
            int4 v = *(const int4*)&deg[i];
            int4 o;
            o.x = run; run += v.x + 1;
            o.y = run; run += v.y + 1;
            o.z = run; run += v.z + 1;
            o.w = run; run += v.w + 1;
            *(int4*)&rowptr[i] = o;
        }
    } else {
        for (int i = begin; i < endi; ++i) {
            rowptr[i] = run;
            run += deg[i] + 1;
        }
    }
    if (t == SCAN_T - 1) rowptr[n] = run;
}

// ---------- edge scoring + exp + CSR placement (atomic-free) ----------
__global__ __launch_bounds__(256) void edge_kernel(const int* __restrict__ ei,
                                                   const float* __restrict__ ea,
                                                   const float* __restrict__ s_src,
                                                   const float* __restrict__ s_dst,
                                                   const float* __restrict__ weff,
                                                   const int* __restrict__ flag,
                                                   const int* __restrict__ rowptr,
                                                   const int* __restrict__ perm,
                                                   int* __restrict__ src_csr,
                                                   float* __restrict__ p_csr,
                                                   int E, int n) {
    __shared__ float we[128];
    if (threadIdx.x < 128) we[threadIdx.x] = weff[threadIdx.x];
    __syncthreads();
    int e = blockIdx.x * blockDim.x + threadIdx.x;
    int EP = E + n;
    if (e >= EP) return;
    int is64 = *flag;
    int s, d;
    load_edge(ei, e, E, n, is64, s, d);
    int pos;
    if (e < E) pos = rowptr[d] + perm[e];
    else       pos = rowptr[d + 1] - 1;   // self-loop takes last slot of bucket
    float4 vs = *(const float4*)&s_src[(size_t)s * 4];
    float4 vd = *(const float4*)&s_dst[(size_t)d * 4];
    float ed[4] = {0.f, 0.f, 0.f, 0.f};
    if (e < E) {
#pragma unroll
        for (int k = 0; k < EDGE_DIM; k += 4) {
            float4 v = *(const float4*)&ea[(size_t)e * EDGE_DIM + k];
#pragma unroll
            for (int h = 0; h < 4; ++h) {
                ed[h] += v.x * we[h * 32 + k + 0] + v.y * we[h * 32 + k + 1] +
                         v.z * we[h * 32 + k + 2] + v.w * we[h * 32 + k + 3];
            }
        }
    }
    float t0 = vs.x + vd.x + ed[0];
    float t1 = vs.y + vd.y + ed[1];
    float t2 = vs.z + vd.z + ed[2];
    float t3 = vs.w + vd.w + ed[3];
    t0 = t0 >= 0.f ? t0 : NEG_SLOPE * t0;
    t1 = t1 >= 0.f ? t1 : NEG_SLOPE * t1;
    t2 = t2 >= 0.f ? t2 : NEG_SLOPE * t2;
    t3 = t3 >= 0.f ? t3 : NEG_SLOPE * t3;
    float4 o;
    o.x = __expf(t0);
    o.y = __expf(t1);
    o.z = __expf(t2);
    o.w = __expf(t3);
    src_csr[pos] = s;
    *(float4*)&p_csr[(size_t)pos * 4] = o;
}

// ---------- aggregation: one wave per node, SINGLE pass, deferred normalization ----------
// out = (sum_e p_e * x[src_e]) / (sum_e p_e + 1e-12) + bias.
// Every lane walks all edges of its node, so each lane accumulates its head's
// denominator in-register: no LDS, no shuffles, no second p_csr read.
__global__ __launch_bounds__(256) void agg_kernel(const int* __restrict__ rowptr,
                                                  const int* __restrict__ src_csr,
                                                  const float* __restrict__ p_csr,
                                                  const _Float16* __restrict__ xph,
                                                  const float* __restrict__ bias,
                                                  float* __restrict__ out, int n) {
    int wid = (blockIdx.x * blockDim.x + threadIdx.x) >> 6;
    int lane = threadIdx.x & 63;
    if (wid >= n) return;
    int start = rowptr[wid];
    int end = rowptr[wid + 1];
    int h = lane >> 4;

    float dh = 0.f, ax = 0.f, ay = 0.f, az = 0.f, aw = 0.f;
    int i = start;
    for (; i + 4 <= end; i += 4) {
        int s0 = src_csr[i + 0];
        int s1 = src_csr[i + 1];
        int s2 = src_csr[i + 2];
        int s3 = src_csr[i + 3];
        float p0 = p_csr[(size_t)(i + 0) * 4 + h];
        float p1 = p_csr[(size_t)(i + 1) * 4 + h];
        float p2 = p_csr[(size_t)(i + 2) * 4 + h];
        float p3 = p_csr[(size_t)(i + 3) * 4 + h];
        f16x4 x0 = *(const f16x4*)&xph[(size_t)s0 * HD + lane * 4];
        f16x4 x1 = *(const f16x4*)&xph[(size_t)s1 * HD + lane * 4];
        f16x4 x2 = *(const f16x4*)&xph[(size_t)s2 * HD + lane * 4];
        f16x4 x3 = *(const f16x4*)&xph[(size_t)s3 * HD + lane * 4];
        dh += (p0 + p1) + (p2 + p3);
        ax += p0 * (float)x0[0] + p1 * (float)x1[0] + p2 * (float)x2[0] + p3 * (float)x3[0];
        ay += p0 * (float)x0[1] + p1 * (float)x1[1] + p2 * (float)x2[1] + p3 * (float)x3[1];
        az += p0 * (float)x0[2] + p1 * (float)x1[2] + p2 * (float)x2[2] + p3 * (float)x3[2];
        aw += p0 * (float)x0[3] + p1 * (float)x1[3] + p2 * (float)x2[3] + p3 * (float)x3[3];
    }
    for (; i < end; ++i) {
        int s0 = src_csr[i];
        float p0 = p_csr[(size_t)i * 4 + h];
        f16x4 x0 = *(const f16x4*)&xph[(size_t)s0 * HD + lane * 4];
        dh += p0;
        ax += p0 * (float)x0[0];
        ay += p0 * (float)x0[1];
        az += p0 * (float)x0[2];
        aw += p0 * (float)x0[3];
    }
    float invh = 1.f / (dh + 1e-12f);
    float4 b = *(const float4*)&bias[lane * 4];
    float4 o4;
    o4.x = ax * invh + b.x;
    o4.y = ay * invh + b.y;
    o4.z = az * invh + b.z;
    o4.w = aw * invh + b.w;
    *(float4*)&out[(size_t)wid * HD + lane * 4] = o4;
}

extern "C" void kernel_launch(void* const* d_in, const int* in_sizes, int n_in,
                              void* d_out, int out_size, void* d_ws, size_t ws_size,
                              hipStream_t stream) {
    const float* x        = (const float*)d_in[0];
    const int*   ei       = (const int*)d_in[1];
    const float* ea       = (const float*)d_in[2];
    const float* lin_W    = (const float*)d_in[3];
    const float* att_src  = (const float*)d_in[4];
    const float* att_dst  = (const float*)d_in[5];
    const float* lin_eW   = (const float*)d_in[6];
    const float* att_edge = (const float*)d_in[7];
    const float* bias     = (const float*)d_in[8];
    float* out = (float*)d_out;

    int n  = in_sizes[0] / IN_DIM;     // 20000
    int E  = in_sizes[2] / EDGE_DIM;   // 320000
    int EP = E + n;

    char* p = (char*)d_ws;
    auto alloc = [&](size_t bytes) {
        char* r = p;
        p += (bytes + 255) & ~(size_t)255;
        return r;
    };
    _Float16* xph   = (_Float16*)alloc((size_t)n * HD * 2);
    _Float16* Wh    = (_Float16*)alloc((size_t)HD * IN_DIM * 2);
    float* s_src    = (float*)alloc((size_t)n * 4 * 4);
    float* s_dst    = (float*)alloc((size_t)n * 4 * 4);
    float* p_csr    = (float*)alloc((size_t)EP * 4 * 4);
    float* weff     = (float*)alloc(128 * 4);
    int*   deg      = (int*)alloc((size_t)(n + 4) * 4);
    int*   rowptr   = (int*)alloc((size_t)(n + 1) * 4);
    int*   perm     = (int*)alloc((size_t)E * 4);
    int*   src_csr  = (int*)alloc((size_t)EP * 4);
    int*   flag     = (int*)alloc(4);

    int n4 = (n + 3) & ~3;
    zero_kernel<<<(n4 / 4 + 255) / 256, 256, 0, stream>>>(deg, n4);
    int hist_blocks = (E + 1023) / 1024;
    prep_kernel<<<2 + WCVT_BLOCKS + hist_blocks, 256, 0, stream>>>(
        ei, lin_eW, att_edge, lin_W, weff, Wh, deg, perm, flag, E, n);
    proj_kernel<<<(n + 15) / 16, 256, 0, stream>>>(x, Wh, att_src, att_dst, xph,
                                                   s_src, s_dst, n);
    scan_kernel<<<1, SCAN_T, 0, stream>>>(deg, rowptr, n);
    edge_kernel<<<(EP + 255) / 256, 256, 0, stream>>>(ei, ea, s_src, s_dst, weff, flag,
                                                      rowptr, perm, src_csr, p_csr, E, n);
    agg_kernel<<<(n + 3) / 4, 256, 0, stream>>>(rowptr, src_csr, p_csr, xph, bias, out, n);
}